// Round 3
// baseline (84.528 us; speedup 1.0000x reference)
//
#include <hip/hip_runtime.h>
#include <math.h>

#ifndef M_PI
#define M_PI 3.14159265358979323846
#endif

#define NPOLE 32     // N2
#define SLEN 2048    // L
#define NHALF 1024   // L/2

// One block (256 threads) per head h; 4 m-nodes per thread to amortize the
// per-wave LDS broadcast reads of pole data (round-2 was LDS-pipe-bound:
// 96 ds_read_b128/wave x 16 waves/CU = 7.7us > 5.5us VALU).
// Analytic facts (omega on unit circle):
//   z = 2(1-omega)/(1+omega) = 2i*tan(pi*m/L)  (purely imaginary)
//   2/(1+omega) = 1 + i*tan(pi*m/L)
// All fp32, raw v_rcp_f32; Nyquist m=1024 via exact limit dt*sum(Re v00).
__global__ __launch_bounds__(256) void s4_nplr_kernel(
    const float* __restrict__ g_log_dt,
    const float* __restrict__ g_log_w_real,
    const float* __restrict__ g_w_imag,
    const float* __restrict__ g_B,
    const float* __restrict__ g_C,
    const float* __restrict__ g_P,
    float* __restrict__ g_out)
{
    const int h   = blockIdx.x;
    const int tid = threadIdx.x;

    __shared__ float4 sA[NPOLE];      // {ar, wim, dt*v00r, dt*v00i}   ar = -Re(w)*dt
    __shared__ float4 sB[NPOLE];      // dt * {v01r, v01i, v10r, v10i}
    __shared__ float  sC[NPOLE];      // dt * v11r
    __shared__ __align__(16) float2 bufA[NHALF];
    __shared__ __align__(16) float2 bufB[NHALF];
    __shared__ float2 stw[512];       // FFT twiddles e^{+i*pi*k/512}
    __shared__ float2 s_kf_last;      // k_f[1024]

    const float dt = expf(g_log_dt[h]);

    if (tid < NPOLE) {
        const int n   = tid;
        const int idx = h * NPOLE + n;
        const float ar  = expf(g_log_w_real[idx]) * dt;   // -Re(w)*dt > 0
        const float wim = g_w_imag[idx] * dt;
        const float Br = g_B[2*idx+0], Bi = g_B[2*idx+1];
        const float Cr = g_C[2*idx+0], Ci = g_C[2*idx+1];
        const float Pr = g_P[2*idx+0], Pi = g_P[2*idx+1];
        // v00=B*C, v01=B*conj(P), v10=P*C, v11=|P|^2 ; dt folded in
        sA[n] = make_float4(ar, wim, dt*(Br*Cr - Bi*Ci), dt*(Br*Ci + Bi*Cr));
        sB[n] = make_float4(dt*(Br*Pr + Bi*Pi), dt*(Bi*Pr - Br*Pi),
                            dt*(Pr*Cr - Pi*Ci), dt*(Pr*Ci + Pi*Cr));
        sC[n] = dt*(Pr*Pr + Pi*Pi);
    }
    // FFT twiddle table: stw[k] = exp(+i*pi*k/512), 2 entries/thread
    for (int k = tid; k < 512; k += 256) {
        float ang = (float)(M_PI / 512.0) * (float)k;
        float sn, cs;
        sincosf(ang, &sn, &cs);
        stw[k] = make_float2(cs, sn);
    }
    __syncthreads();

    // ---- Phase B: 4 m-nodes per thread (m = tid + 256*j) ----
    float tj[4], t2[4];
    #pragma unroll
    for (int j = 0; j < 4; ++j) {
        tj[j] = tanf((float)(tid + (j << 8)) * (float)(M_PI / 2048.0));
        t2[j] = tj[j] + tj[j];
    }
    float acc[4][8];
    #pragma unroll
    for (int j = 0; j < 4; ++j)
        #pragma unroll
        for (int q = 0; q < 8; ++q) acc[j][q] = 0.0f;

    #pragma unroll 2
    for (int n = 0; n < NPOLE; ++n) {
        const float4 a  = sA[n];      // broadcast LDS reads, amortized over 4 nodes
        const float4 b  = sB[n];
        const float v11 = sC[n];
        const float ar = a.x, wim = a.y;
        const float ar2 = ar * ar;
        #pragma unroll
        for (int j = 0; j < 4; ++j) {
            float aim = t2[j] - wim, aip = t2[j] + wim;
            float inv1 = __builtin_amdgcn_rcpf(fmaf(aim, aim, ar2));
            float inv2 = __builtin_amdgcn_rcpf(fmaf(aip, aip, ar2));
            float d1r = ar * inv1,   e2r = ar * inv2;
            float d1i = -aim * inv1, e2i = -aip * inv2;
            float Sr = d1r + e2r, Dr = d1r - e2r;
            float Si = d1i + e2i, Di = e2i - d1i;
            acc[j][0] = fmaf(a.z, Sr, fmaf(a.w, Di, acc[j][0]));   // r00
            acc[j][1] = fmaf(a.z, Si, fmaf(a.w, Dr, acc[j][1]));
            acc[j][2] = fmaf(b.x, Sr, fmaf(b.y, Di, acc[j][2]));   // r01
            acc[j][3] = fmaf(b.x, Si, fmaf(b.y, Dr, acc[j][3]));
            acc[j][4] = fmaf(b.z, Sr, fmaf(b.w, Di, acc[j][4]));   // r10
            acc[j][5] = fmaf(b.z, Si, fmaf(b.w, Dr, acc[j][5]));
            acc[j][6] = fmaf(v11, Sr, acc[j][6]);                  // r11 (v11 real)
            acc[j][7] = fmaf(v11, Si, acc[j][7]);
        }
    }

    // Woodbury + spectral factor (1 + i*t) per node
    #pragma unroll
    for (int j = 0; j < 4; ++j) {
        float wdr = 1.0f + acc[j][6], wdi = acc[j][7];
        float winv = __builtin_amdgcn_rcpf(fmaf(wdr, wdr, wdi*wdi));
        float trm = acc[j][2]*acc[j][4] - acc[j][3]*acc[j][5];
        float tim = acc[j][2]*acc[j][5] + acc[j][3]*acc[j][4];
        float cr = (trm*wdr + tim*wdi) * winv;
        float ci = (tim*wdr - trm*wdi) * winv;
        float kr = acc[j][0] - cr, ki = acc[j][1] - ci;
        bufA[tid + (j << 8)] = make_float2(fmaf(-ki, tj[j], kr), fmaf(kr, tj[j], ki));
    }
    // Nyquist m=1024: exact limit k_f = dt * sum_n Re(v00_n)
    if (tid == 0) {
        float s = 0.0f;
        #pragma unroll
        for (int n = 0; n < NPOLE; ++n) s += sA[n].z;
        s_kf_last = make_float2(s, 0.0f);
    }
    __syncthreads();

    // ---- Phase C1: hermitian pack X[0..1024] -> Y[0..1023] in bufB ----
    #pragma unroll
    for (int jj = 0; jj < 4; ++jj) {
        const int l = tid + (jj << 8);
        float2 Xm = bufA[l];
        float2 Xn = (l == 0) ? s_kf_last : bufA[NHALF - l];
        if (l == 0) { Xm.y = 0.0f; Xn.y = 0.0f; }   // numpy C2R: DC/Nyquist imag ignored
        float er  = 0.5f*(Xm.x + Xn.x);
        float ei  = 0.5f*(Xm.y - Xn.y);
        float odr = 0.5f*(Xm.x - Xn.x);
        float odi = 0.5f*(Xm.y + Xn.y);
        float ang = (float)(M_PI/1024.0) * (float)l;  // +2*pi*l/L
        float sn, cs;
        sincosf(ang, &sn, &cs);
        float Or = odr*cs - odi*sn;
        float Oi = odr*sn + odi*cs;
        bufB[l] = make_float2(er - Oi, ei + Or);
    }
    __syncthreads();

    // ---- Phase C2: Stockham radix-2 inverse FFT, N=1024, 10 stages ----
    float2* src = bufB;
    float2* dst = bufA;
    int s = 1;
    for (int t = 0; t < 10; ++t) {
        #pragma unroll
        for (int j = 0; j < 2; ++j) {
            const int i    = tid + (j << 8);      // 0..511
            const int lo   = i & (s - 1);
            const int base = i - lo;              // s*p in [0,512)
            float2 twf = stw[base];
            float2 a = src[i];
            float2 b = src[i + 512];
            float2 sum = make_float2(a.x + b.x, a.y + b.y);
            float2 dif = make_float2(a.x - b.x, a.y - b.y);
            float2 tw  = make_float2(dif.x*twf.x - dif.y*twf.y,
                                     dif.x*twf.y + dif.y*twf.x);
            const int o = base*2 + lo;
            dst[o]     = sum;
            dst[o + s] = tw;
        }
        __syncthreads();
        float2* tmp = src; src = dst; dst = tmp;
        s <<= 1;
    }
    // after 10 swaps the result sits in `src` (== bufB)

    // ---- store: x[2l] = Re(y[l])/N, x[2l+1] = Im(y[l])/N ; 2x float4/thread ----
    const float scale = 1.0f / (float)NHALF;
    float4* outp = (float4*)(g_out + (size_t)h * SLEN);
    #pragma unroll
    for (int l = tid; l < 512; l += 256) {
        const float4 y2 = *((const float4*)&src[2*l]);
        outp[l] = make_float4(y2.x*scale, y2.y*scale, y2.z*scale, y2.w*scale);
    }
}

extern "C" void kernel_launch(void* const* d_in, const int* in_sizes, int n_in,
                              void* d_out, int out_size, void* d_ws, size_t ws_size,
                              hipStream_t stream) {
    const float* log_dt     = (const float*)d_in[0];
    const float* log_w_real = (const float*)d_in[1];
    const float* w_imag     = (const float*)d_in[2];
    const float* B          = (const float*)d_in[3];
    const float* C          = (const float*)d_in[4];
    const float* P          = (const float*)d_in[5];
    float* out = (float*)d_out;
    const int H = in_sizes[0];   // 512
    s4_nplr_kernel<<<H, 256, 0, stream>>>(log_dt, log_w_real, w_imag, B, C, P, out);
}